// Round 5
// baseline (109.525 us; speedup 1.0000x reference)
//
#include <hip/hip_runtime.h>
#include <hip/hip_fp16.h>

#define BATCH 2048

typedef _Float16 f16x8 __attribute__((ext_vector_type(8)));
typedef float f32x4 __attribute__((ext_vector_type(4)));

// xsc geometry (halves): 4 shift planes (s=0..3), ONE image at a time.
// Plane s holds, at position p, original col p+s -> every A-frag read
// starts at (c-s) % 4 == 0 halves = 8B aligned -> 2 x b64 per frag.
// Strides bank-verified in r2: CST = 584 dwords % 32 == 8, RST = 18 dwords.
#define RST 36        // row stride (halves): 32 data + 4 (never read)
#define CST 1168      // plane stride: 32*36 + 16 pad
#define PIS 3152      // ps image stride (halves): 49*64 + 16 (/2 % 32 == 8)

__device__ __forceinline__ float fast_sigmoid(float v) {
    return __builtin_amdgcn_rcpf(1.0f + __builtin_amdgcn_exp2f(v * -1.44269504f));
}

// ---------------------------------------------------------------------------
// Workspace layout (bytes):
//   [0      .. 301056)  W3B  tree B-frags f16 [gi 21][c 14][lane 64][8h]
//   [301056 .. 314496)  FCW2 f32 [g 3][o 10][i 7][f 16]
// ---------------------------------------------------------------------------
#define WS_W3B  0
#define WS_FCW  301056

// k_prep: coalesced float4 read of tree_w + scattered 2B stores.
__global__ __launch_bounds__(256) void k_prep(
    const float* __restrict__ tree_w,
    const float* __restrict__ fc_w,
    ushort* __restrict__ W3B,
    float* __restrict__ FCW2,
    float* __restrict__ out)
{
    int pidx = blockIdx.x * 256 + threadIdx.x;
    if (pidx < 35280) {                     // W3B scatter: 141120 f32 / 4
        float4 v = ((const float4*)tree_w)[pidx];
        int j  = pidx % 7;
        int t1 = pidx / 7;
        int i  = t1 % 7;
        int t2 = t1 / 7;
        int g  = t2 % 3;
        int t3 = t2 / 3;
        int nn = t3 % 15;
        int f  = t3 / 15;
        int gi = g * 7 + i;
        int u  = nn & 7;
        int hi = nn >> 3;
        float vv[4] = {v.x, v.y, v.z, v.w};
        #pragma unroll
        for (int e = 0; e < 4; e++) {
            int ki = e >> 1, kj = e & 1;
            int u27 = ki * 14 + j * 2 + kj;
            int c   = u27 >> 1;
            int qq  = (u27 & 1) * 2 + hi;
            W3B[(size_t)(gi * 14 + c) * 512 + (qq * 16 + f) * 8 + u] =
                __half_as_ushort(__float2half(vv[e]));
        }
    } else if (pidx < 38640) {              // FCW2: 3*10*7*16 f32
        int jj = pidx - 35280;
        int f = jj & 15;
        int r = jj >> 4;
        int i = r % 7;
        int r2 = r / 7;
        int o = r2 % 10;
        int g = r2 / 10;
        FCW2[jj] = fc_w[o * 336 + f * 21 + g * 7 + i];
    } else if (pidx < 48048) {              // zero nn==15 slots (qq odd, u=7)
        int z = pidx - 38640;
        int f  = z & 15;
        int qq = ((z >> 4) & 1) * 2 + 1;
        int r  = z >> 5;
        int c  = r % 14;
        int gi = r / 14;
        W3B[(size_t)(gi * 14 + c) * 512 + (qq * 16 + f) * 8 + 7] = 0;
    } else if (pidx < 68528) {              // zero out[2048][10]
        out[pidx - 48048] = 0.f;
    }
}

// ---------------------------------------------------------------------------
// kF_all: per (image-quad, g).  r5: back to r2's verified 4-plane layout
// (b64 A-frag reads, 2.3x fewer LDS issue slots on the conv hot path) but
// single-image xsc rounds so LDS stays at 34.5 KB -> 4 blocks/CU (r3's
// occupancy).  r4's exec-masked A2 and odd-stride reverted (LDS issue
// slots are wave-level; masking lanes saves nothing).  Bf prefetch kept.
// LDS: xsc 9,344 + ps 25,216 = 34,560 B.
// ---------------------------------------------------------------------------
__global__ __launch_bounds__(256, 4) void kF_all(
    const float* __restrict__ x,       // [B][3][32][32]
    const float* __restrict__ conv_w,  // [45][25]
    const float* __restrict__ conv_b,  // [45]
    const ushort* __restrict__ W3B,
    const float* __restrict__ FCW2,    // [3][10][7][16] f32
    const float* __restrict__ tree_b,  // [336]
    const float* __restrict__ fc_b,    // [10]
    float* __restrict__ out)           // [2048][10] (zeroed by k_prep)
{
    __shared__ __align__(16) ushort xsc[4 * CST];   // 9,344 B (one image)
    __shared__ __align__(16) ushort ps[4 * PIS];    // 25,216 B
    ushort* tsl = xsc;                 // [28][16], alias (xsc dead after conv)

    const int tid  = threadIdx.x;
    const int blk  = blockIdx.x;
    const int quad = blk / 3;
    const int g    = blk - quad * 3;
    const int img0 = quad * 4;
    const int lane = tid & 63;
    const int n    = lane & 15;
    const int q    = lane >> 4;
    const int wave = tid >> 6;

    // ---- issue all 4 images' channel-g plane loads early ----
    float4 xv[4];
    #pragma unroll
    for (int im = 0; im < 4; im++)
        xv[im] = ((const float4*)(x + (size_t)(img0 + im) * 3072 + g * 1024))[tid];

    // ---- conv B-frags + folded bias (bs = -bias*log2(e)) ----
    f16x8 B1 = {0, 0, 0, 0, 0, 0, 0, 0};
    f16x8 B2 = {0, 0, 0, 0, 0, 0, 0, 0};
    float bs = 0.f;
    if (n < 15) {
        const float* wrow = conv_w + (g * 15 + n) * 25;
        #pragma unroll
        for (int u = 0; u < 5; u++) B1[u] = (_Float16)wrow[q * 5 + u];
        if (q == 0) {
            #pragma unroll
            for (int u = 0; u < 5; u++) B2[u] = (_Float16)wrow[20 + u];
        }
        bs = conv_b[g * 15 + n] * -1.44269504f;
    }

    // ---- per-lane conv A offsets (halves), wrap-recurrence, no divides ----
    // aoff = s*CST + (r+q)*RST + (c-s), s = 2*(pw&1)+dc, c-s = 4*(pw>>1)
    const int dr = (n >> 1) & 1, dc = n & 1, n4 = n >> 2;
    const int a2c = (4 - q) * RST;     // row r+q -> row r+4
    int aoff[13];
    {
        int pb = wave * 4 + n4;        // 0..15
        int ph = (pb >= 14) ? 1 : 0;
        int pw = pb - 14 * ph;
        const int rbase = (dr + q) * RST;
        #pragma unroll
        for (int it = 0; it < 13; it++) {
            int s = 2 * (pw & 1) + dc;
            aoff[it] = s * CST + rbase + 2 * ph * RST + 4 * (pw >> 1);
            pw += 2; ph += 1;
            if (pw >= 14) { pw -= 14; ph += 1; }
        }
    }

    // ---- fused pack of one image into 4 shift planes (r2's values) ----
    const int prow = tid >> 3, pt = tid & 7;
    ushort* const pbase = xsc + prow * RST + pt * 4;
    auto pack_img = [&](float4 v) {
        __half2 a = __float22half2_rn(make_float2(v.x, v.y));
        __half2 b = __float22half2_rn(make_float2(v.z, v.w));
        unsigned d0 = *(unsigned*)&a, d1 = *(unsigned*)&b;
        unsigned n0 = (unsigned)__shfl_down((int)d0, 1);
        unsigned n1 = (unsigned)__shfl_down((int)d1, 1);
        if (pt == 7) { n0 = 0u; n1 = 0u; }          // cols 32.. = 0
        unsigned t01 = (d0 >> 16) | (d1 << 16);     // cols +1,+2
        unsigned t12 = (d1 >> 16) | (n0 << 16);     // cols +3,+4
        unsigned t23 = (n0 >> 16) | (n1 << 16);     // cols +5,+6
        *(uint2*)(pbase)           = make_uint2(d0, d1);    // s=0
        *(uint2*)(pbase + CST)     = make_uint2(t01, t12);  // s=1
        *(uint2*)(pbase + 2 * CST) = make_uint2(d1, n0);    // s=2
        *(uint2*)(pbase + 3 * CST) = make_uint2(t12, t23);  // s=3
    };

    // ---- conv tile: one image, 2 b64 per frag ----
    auto conv_tile = [&](int it, ushort* pso) {
        const ushort* pA = xsc + aoff[it];
        union U { struct { uint2 a, b; } u; f16x8 v; };
        U A1, A2;
        A1.u.a = *(const uint2*)pA;
        A1.u.b = *(const uint2*)(pA + 4);
        A2.u.a = *(const uint2*)(pA + a2c);
        A2.u.b = *(const uint2*)(pA + a2c + 4);
        f32x4 d = {0.f, 0.f, 0.f, 0.f};
        d = __builtin_amdgcn_mfma_f32_16x16x32_f16(A1.v, B1, d, 0, 0, 0);
        d = __builtin_amdgcn_mfma_f32_16x16x32_f16(A2.v, B2, d, 0, 0, 0);
        float mx = fmaxf(fmaxf(d[0], d[1]), fmaxf(d[2], d[3]));
        float e = __builtin_amdgcn_exp2f(fmaf(mx, -1.44269504f, bs));
        pso[(wave + it * 4) * 64 + lane] =
            __half_as_ushort(__float2half(__builtin_amdgcn_rcpf(1.0f + e)));
    };

    f16x8 Bf[14];

    // ---- 4 rounds: pack image -> conv+pool -> ps[rr] ----
    #pragma unroll
    for (int rr = 0; rr < 4; rr++) {
        pack_img(xv[rr]);
        __syncthreads();
        if (rr == 3) {   // prefetch first tree GEMM's B-frags under last conv
            const f16x8* Wb = (const f16x8*)W3B + (size_t)(g * 7 + wave) * 896;
            #pragma unroll
            for (int c = 0; c < 14; c++) Bf[c] = Wb[c * 64 + lane];
        }
        ushort* pso = ps + rr * PIS;
        #pragma unroll
        for (int it = 0; it < 12; it++) conv_tile(it, pso);
        if (wave == 0) conv_tile(12, pso);
        __syncthreads();
    }

    // ---- tree: 7 per-i GEMMs over waves; M=4 images via lane&3 ----
    auto tree_gemm = [&](int ii) {
        const ushort* ap = ps + (n & 3) * PIS + ii * 448;
        f32x4 D0 = {0.f, 0.f, 0.f, 0.f};
        f32x4 D1 = {0.f, 0.f, 0.f, 0.f};
        #pragma unroll
        for (int c = 0; c < 7; c++) {
            f16x8 Ae = *(const f16x8*)(ap + (2 * c) * 32 + q * 8);
            D0 = __builtin_amdgcn_mfma_f32_16x16x32_f16(Ae, Bf[2 * c], D0, 0, 0, 0);
            f16x8 Ao = *(const f16x8*)(ap + (2 * c + 1) * 32 + q * 8);
            D1 = __builtin_amdgcn_mfma_f32_16x16x32_f16(Ao, Bf[2 * c + 1], D1, 0, 0, 0);
        }
        if (q == 0) {                  // rows 0..3 = images 0..3
            float tb = tree_b[n * 21 + g * 7 + ii];
            #pragma unroll
            for (int im = 0; im < 4; im++) {
                float t = (D0[im] + D1[im]) + tb;
                tsl[(im * 7 + ii) * 16 + n] =
                    __half_as_ushort(__float2half(fast_sigmoid(t)));
            }
        }
    };

    tree_gemm(wave);
    if (wave < 3) {
        const f16x8* Wb = (const f16x8*)W3B + (size_t)(g * 7 + wave + 4) * 896;
        #pragma unroll
        for (int c = 0; c < 14; c++) Bf[c] = Wb[c * 64 + lane];
        tree_gemm(wave + 4);
    }
    __syncthreads();

    // ---- partial FC: wave w handles image w, lanes 0..9 = o; atomic add ----
    if (lane < 10) {
        const int im4 = wave, o = lane;
        const uint2* tp = (const uint2*)(tsl + im4 * 112);
        const float4* wp = (const float4*)(FCW2 + (size_t)(g * 10 + o) * 112);
        float acc = (g == 0) ? fc_b[o] : 0.f;
        #pragma unroll
        for (int jj = 0; jj < 28; jj++) {
            float4 w4 = wp[jj];
            uint2 hv = tp[jj];
            float2 p0 = __half22float2(*(const __half2*)&hv.x);
            float2 p1 = __half22float2(*(const __half2*)&hv.y);
            acc = fmaf(p0.x, w4.x, acc);
            acc = fmaf(p0.y, w4.y, acc);
            acc = fmaf(p1.x, w4.z, acc);
            acc = fmaf(p1.y, w4.w, acc);
        }
#if defined(__HIP_PLATFORM_AMD__)
        unsafeAtomicAdd(out + (size_t)(img0 + im4) * 10 + o, acc);
#else
        atomicAdd(out + (size_t)(img0 + im4) * 10 + o, acc);
#endif
    }
}

extern "C" void kernel_launch(void* const* d_in, const int* in_sizes, int n_in,
                              void* d_out, int out_size, void* d_ws, size_t ws_size,
                              hipStream_t stream) {
    const float* x      = (const float*)d_in[0];
    const float* conv_w = (const float*)d_in[1];
    const float* conv_b = (const float*)d_in[2];
    const float* tree_w = (const float*)d_in[3];
    const float* tree_b = (const float*)d_in[4];
    const float* fc_w   = (const float*)d_in[5];
    const float* fc_b   = (const float*)d_in[6];
    float* out = (float*)d_out;

    ushort* W3B  = (ushort*)((char*)d_ws + WS_W3B);
    float*  FCW2 = (float*)((char*)d_ws + WS_FCW);

    k_prep<<<268, 256, 0, stream>>>(tree_w, fc_w, W3B, FCW2, out);
    kF_all<<<512 * 3, 256, 0, stream>>>(x, conv_w, conv_b, W3B, FCW2,
                                        tree_b, fc_b, out);
}

// Round 6
// 101.806 us; speedup vs baseline: 1.0758x; 1.0758x over previous
//
#include <hip/hip_runtime.h>
#include <hip/hip_fp16.h>

#define BATCH 2048

typedef _Float16 f16x8 __attribute__((ext_vector_type(8)));
typedef float f32x4 __attribute__((ext_vector_type(4)));

// xsc geometry (dwords): 2 planes (s=0 even-shift, s=1 odd-shift), ONE image
// at a time; shifts 2,3 are dword-offset reads of planes 0,1.  Identical
// addressing to the verified r3 kernel (102.3 us), just single-image.
#define XROW 18       // row stride (dwords): 16 data + 2 pad (zeroed)
#define XPL  584      // plane stride: 32*18 + 8  (%32 == 8 for bank spread)
#define PIS  3152     // ps image stride (ushorts): 49*64 + 16 (/2 %32 == 8)

__device__ __forceinline__ float fast_sigmoid(float v) {
    return __builtin_amdgcn_rcpf(1.0f + __builtin_amdgcn_exp2f(v * -1.44269504f));
}

// ---------------------------------------------------------------------------
// Workspace layout (bytes):
//   [0      .. 301056)  W3B  tree B-frags f16 [gi 21][c 14][lane 64][8h]
//   [301056 .. 314496)  FCW2 f32 [g 3][o 10][i 7][f 16]
// ---------------------------------------------------------------------------
#define WS_W3B  0
#define WS_FCW  301056

// k_prep: coalesced float4 read of tree_w + scattered 2B stores.
__global__ __launch_bounds__(256) void k_prep(
    const float* __restrict__ tree_w,
    const float* __restrict__ fc_w,
    ushort* __restrict__ W3B,
    float* __restrict__ FCW2,
    float* __restrict__ out)
{
    int pidx = blockIdx.x * 256 + threadIdx.x;
    if (pidx < 35280) {                     // W3B scatter: 141120 f32 / 4
        float4 v = ((const float4*)tree_w)[pidx];
        int j  = pidx % 7;
        int t1 = pidx / 7;
        int i  = t1 % 7;
        int t2 = t1 / 7;
        int g  = t2 % 3;
        int t3 = t2 / 3;
        int nn = t3 % 15;
        int f  = t3 / 15;
        int gi = g * 7 + i;
        int u  = nn & 7;
        int hi = nn >> 3;
        float vv[4] = {v.x, v.y, v.z, v.w};
        #pragma unroll
        for (int e = 0; e < 4; e++) {
            int ki = e >> 1, kj = e & 1;
            int u27 = ki * 14 + j * 2 + kj;
            int c   = u27 >> 1;
            int qq  = (u27 & 1) * 2 + hi;
            W3B[(size_t)(gi * 14 + c) * 512 + (qq * 16 + f) * 8 + u] =
                __half_as_ushort(__float2half(vv[e]));
        }
    } else if (pidx < 38640) {              // FCW2: 3*10*7*16 f32
        int jj = pidx - 35280;
        int f = jj & 15;
        int r = jj >> 4;
        int i = r % 7;
        int r2 = r / 7;
        int o = r2 % 10;
        int g = r2 / 10;
        FCW2[jj] = fc_w[o * 336 + f * 21 + g * 7 + i];
    } else if (pidx < 48048) {              // zero nn==15 slots (qq odd, u=7)
        int z = pidx - 38640;
        int f  = z & 15;
        int qq = ((z >> 4) & 1) * 2 + 1;
        int r  = z >> 5;
        int c  = r % 14;
        int gi = r / 14;
        W3B[(size_t)(gi * 14 + c) * 512 + (qq * 16 + f) * 8 + 7] = 0;
    } else if (pidx < 68528) {              // zero out[2048][10]
        out[pidx - 48048] = 0.f;
    }
}

// ---------------------------------------------------------------------------
// kF_all r6: r3's exact conv addressing (2-plane dword-shift layout, full
// unmasked A2, even strides) but xsc holds ONE image -> LDS 4,672 + 25,216
// = 29,888 B -> 5 blocks/CU (20 waves, +25% TLP vs r3's 4 blocks).
// Bf prefetch REMOVED (suspected VGPR-spill cause of r4/r5 regressions).
// 4 conv rounds (pack -> sync -> conv -> sync), then r3's tree + FC verbatim.
// ---------------------------------------------------------------------------
__global__ __launch_bounds__(256, 5) void kF_all(
    const float* __restrict__ x,       // [B][3][32][32]
    const float* __restrict__ conv_w,  // [45][25]
    const float* __restrict__ conv_b,  // [45]
    const ushort* __restrict__ W3B,
    const float* __restrict__ FCW2,    // [3][10][7][16] f32
    const float* __restrict__ tree_b,  // [336]
    const float* __restrict__ fc_b,    // [10]
    float* __restrict__ out)           // [2048][10] (zeroed by k_prep)
{
    __shared__ __align__(16) unsigned xsc[2 * XPL];   // 4,672 B (one image)
    __shared__ __align__(16) ushort ps[4 * PIS];      // 25,216 B
    ushort* tsl = (ushort*)xsc;        // [28][16], alias (xsc dead after conv)

    const int tid  = threadIdx.x;
    const int blk  = blockIdx.x;
    const int quad = blk / 3;
    const int g    = blk - quad * 3;
    const int img0 = quad * 4;
    const int lane = tid & 63;
    const int n    = lane & 15;
    const int q    = lane >> 4;
    const int wave = tid >> 6;

    // ---- issue all 4 images' channel-g plane loads early ----
    float4 xv[4];
    #pragma unroll
    for (int im = 0; im < 4; im++)
        xv[im] = ((const float4*)(x + (size_t)(img0 + im) * 3072 + g * 1024))[tid];

    // ---- zero pad dwords 16,17 of every row/plane (persists: packs only
    //      touch dwords 0..15) ----
    if (tid < 64) {
        int pl = tid >> 5, row = tid & 31;
        *(uint2*)&xsc[pl * XPL + row * XROW + 16] = make_uint2(0u, 0u);
    }

    // ---- conv B-frags + folded bias (bs = -bias*log2(e)) ----
    f16x8 B1 = {0, 0, 0, 0, 0, 0, 0, 0};
    f16x8 B2 = {0, 0, 0, 0, 0, 0, 0, 0};
    float bs = 0.f;
    if (n < 15) {
        const float* wrow = conv_w + (g * 15 + n) * 25;
        #pragma unroll
        for (int u = 0; u < 5; u++) B1[u] = (_Float16)wrow[q * 5 + u];
        if (q == 0) {
            #pragma unroll
            for (int u = 0; u < 5; u++) B2[u] = (_Float16)wrow[20 + u];
        }
        bs = conv_b[g * 15 + n] * -1.44269504f;
    }

    // ---- per-lane conv A offsets (dwords), wrap-recurrence, no divides ----
    const int dr = (n >> 1) & 1, dc = n & 1, n4 = n >> 2;
    const int a2cd = (4 - q) * XROW;   // row r+q -> row r+4
    int aoffd[13];
    {
        int pb = wave * 4 + n4;        // 0..15
        int ph = (pb >= 14) ? 1 : 0;
        int pw = pb - 14 * ph;
        int base = dc * XPL + (dr + q) * XROW;
        #pragma unroll
        for (int it = 0; it < 13; it++) {
            aoffd[it] = base + 2 * ph * XROW + pw;
            pw += 2; ph += 1;
            if (pw >= 14) { pw -= 14; ph += 1; }
        }
    }

    // ---- fused pack of one image: plane0 {d0,d1}, plane1 {t01,t12} ----
    const int prow = tid >> 3, pt = tid & 7;
    unsigned* const pbase = xsc + prow * XROW + 2 * pt;
    auto pack_img = [&](float4 v) {
        __half2 a = __float22half2_rn(make_float2(v.x, v.y));
        __half2 b = __float22half2_rn(make_float2(v.z, v.w));
        unsigned d0 = *(unsigned*)&a, d1 = *(unsigned*)&b;
        unsigned n0 = (unsigned)__shfl_down((int)d0, 1);
        if (pt == 7) n0 = 0u;                       // col 32 = 0
        unsigned t01 = (d0 >> 16) | (d1 << 16);     // cols +1,+2
        unsigned t12 = (d1 >> 16) | (n0 << 16);     // cols +3,+4
        *(uint2*)(pbase)       = make_uint2(d0, d1);
        *(uint2*)(pbase + XPL) = make_uint2(t01, t12);
    };

    // ---- conv tile: one image (r3 addressing, full unmasked A2) ----
    auto conv_tile = [&](int it, ushort* pso) {
        const unsigned* p0 = xsc + aoffd[it];
        union U { unsigned w[4]; f16x8 v; };
        U A1, A2;
        #pragma unroll
        for (int e = 0; e < 4; e++) {
            A1.w[e] = p0[e];
            A2.w[e] = p0[a2cd + e];
        }
        f32x4 d = {0.f, 0.f, 0.f, 0.f};
        d = __builtin_amdgcn_mfma_f32_16x16x32_f16(A1.v, B1, d, 0, 0, 0);
        d = __builtin_amdgcn_mfma_f32_16x16x32_f16(A2.v, B2, d, 0, 0, 0);
        float mx = fmaxf(fmaxf(d[0], d[1]), fmaxf(d[2], d[3]));
        float e = __builtin_amdgcn_exp2f(fmaf(mx, -1.44269504f, bs));
        pso[(wave + it * 4) * 64 + lane] =
            __half_as_ushort(__float2half(__builtin_amdgcn_rcpf(1.0f + e)));
    };

    // ---- 4 rounds: pack image -> conv+pool -> ps[rr] ----
    #pragma unroll
    for (int rr = 0; rr < 4; rr++) {
        pack_img(xv[rr]);
        __syncthreads();
        ushort* pso = ps + rr * PIS;
        #pragma unroll
        for (int it = 0; it < 12; it++) conv_tile(it, pso);
        if (wave == 0) conv_tile(12, pso);
        __syncthreads();
    }

    // ---- tree: 7 per-i GEMMs over waves; M=4 images via lane&3 (r3) ----
    for (int ii = wave; ii < 7; ii += 4) {
        const f16x8* Wb = (const f16x8*)W3B + (size_t)(g * 7 + ii) * 896;
        const ushort* ap = ps + (n & 3) * PIS + ii * 448;
        f16x8 Bf[14];
        #pragma unroll
        for (int c = 0; c < 14; c++) Bf[c] = Wb[c * 64 + lane];
        f32x4 D0 = {0.f, 0.f, 0.f, 0.f};
        f32x4 D1 = {0.f, 0.f, 0.f, 0.f};
        #pragma unroll
        for (int c = 0; c < 7; c++) {
            f16x8 Ae = *(const f16x8*)(ap + (2 * c) * 32 + q * 8);
            D0 = __builtin_amdgcn_mfma_f32_16x16x32_f16(Ae, Bf[2 * c], D0, 0, 0, 0);
            f16x8 Ao = *(const f16x8*)(ap + (2 * c + 1) * 32 + q * 8);
            D1 = __builtin_amdgcn_mfma_f32_16x16x32_f16(Ao, Bf[2 * c + 1], D1, 0, 0, 0);
        }
        if (q == 0) {                  // rows 0..3 = images 0..3
            float tb = tree_b[n * 21 + g * 7 + ii];
            #pragma unroll
            for (int im = 0; im < 4; im++) {
                float t = (D0[im] + D1[im]) + tb;
                tsl[(im * 7 + ii) * 16 + n] =
                    __half_as_ushort(__float2half(fast_sigmoid(t)));
            }
        }
    }
    __syncthreads();

    // ---- partial FC: wave w handles image w, lanes 0..9 = o; atomic add ----
    if (lane < 10) {
        const int im4 = wave, o = lane;
        const uint2* tp = (const uint2*)(tsl + im4 * 112);
        const float4* wp = (const float4*)(FCW2 + (size_t)(g * 10 + o) * 112);
        float acc = (g == 0) ? fc_b[o] : 0.f;
        #pragma unroll
        for (int jj = 0; jj < 28; jj++) {
            float4 w4 = wp[jj];
            uint2 hv = tp[jj];
            float2 p0 = __half22float2(*(const __half2*)&hv.x);
            float2 p1 = __half22float2(*(const __half2*)&hv.y);
            acc = fmaf(p0.x, w4.x, acc);
            acc = fmaf(p0.y, w4.y, acc);
            acc = fmaf(p1.x, w4.z, acc);
            acc = fmaf(p1.y, w4.w, acc);
        }
#if defined(__HIP_PLATFORM_AMD__)
        unsafeAtomicAdd(out + (size_t)(img0 + im4) * 10 + o, acc);
#else
        atomicAdd(out + (size_t)(img0 + im4) * 10 + o, acc);
#endif
    }
}

extern "C" void kernel_launch(void* const* d_in, const int* in_sizes, int n_in,
                              void* d_out, int out_size, void* d_ws, size_t ws_size,
                              hipStream_t stream) {
    const float* x      = (const float*)d_in[0];
    const float* conv_w = (const float*)d_in[1];
    const float* conv_b = (const float*)d_in[2];
    const float* tree_w = (const float*)d_in[3];
    const float* tree_b = (const float*)d_in[4];
    const float* fc_w   = (const float*)d_in[5];
    const float* fc_b   = (const float*)d_in[6];
    float* out = (float*)d_out;

    ushort* W3B  = (ushort*)((char*)d_ws + WS_W3B);
    float*  FCW2 = (float*)((char*)d_ws + WS_FCW);

    k_prep<<<268, 256, 0, stream>>>(tree_w, fc_w, W3B, FCW2, out);
    kF_all<<<512 * 3, 256, 0, stream>>>(x, conv_w, conv_b, W3B, FCW2,
                                        tree_b, fc_b, out);
}